// Round 1
// baseline (74020.087 us; speedup 1.0000x reference)
//
#include <hip/hip_runtime.h>

#define BPATHS 8192
#define TSTEPS 2048
#define W 64
#define PPB 32      // paths per block (lane p = tid & 31)
#define SLICES 8    // hidden-dim slices (s = tid >> 5)
#define JPW 8       // hidden units per thread = W / SLICES
#define NT 256      // threads per block
#define HSTR 65     // padded stride for activation LDS rows (bank-conflict-free)

#define KAPPA 2.72f
#define THETA -3.5f

__device__ __forceinline__ float ftanh(float x) {
    // tanh(x) = 1 - 2/(e^{2x}+1); safe at +/-inf (e=inf -> 1, e=0 -> -1)
    float e = __expf(2.0f * x);
    return 1.0f - 2.0f * __builtin_amdgcn_rcpf(e + 1.0f);
}

__device__ __forceinline__ float fsigm(float x) {
    return __builtin_amdgcn_rcpf(1.0f + __expf(-x));
}

struct MlpW {
    const float* w0;   // [64][15] row-major
    const float* b0;   // [64]
    const float* w1T;  // [k][j] = w1[j][k]
    const float* b1;
    const float* w2T;
    const float* b2;
    const float* w3;   // [64]
    float b3;
};

__device__ __forceinline__ float mlp_eval(const float* x, const MlpW& m,
                                          float* hA, float* hB, float* part,
                                          int p, int s) {
    const int j0 = s * JPW;
    // ---- L0: 15 -> 64 (x is in registers, replicated per thread) ----
    {
        float acc[JPW];
#pragma unroll
        for (int jj = 0; jj < JPW; ++jj) acc[jj] = m.b0[j0 + jj];
#pragma unroll
        for (int k = 0; k < 15; ++k) {
            float xv = x[k];
#pragma unroll
            for (int jj = 0; jj < JPW; ++jj)
                acc[jj] = fmaf(xv, m.w0[(j0 + jj) * 15 + k], acc[jj]);
        }
#pragma unroll
        for (int jj = 0; jj < JPW; ++jj) hA[p * HSTR + j0 + jj] = ftanh(acc[jj]);
    }
    __syncthreads();
    // ---- L1: 64 -> 64, hA -> hB ----
    {
        float acc[JPW];
#pragma unroll
        for (int jj = 0; jj < JPW; ++jj) acc[jj] = m.b1[j0 + jj];
#pragma unroll 16
        for (int k = 0; k < W; ++k) {
            float hk = hA[p * HSTR + k];
#pragma unroll
            for (int jj = 0; jj < JPW; ++jj)
                acc[jj] = fmaf(hk, m.w1T[k * W + j0 + jj], acc[jj]);
        }
#pragma unroll
        for (int jj = 0; jj < JPW; ++jj) hB[p * HSTR + j0 + jj] = ftanh(acc[jj]);
    }
    __syncthreads();
    // ---- L2: 64 -> 64, hB -> hA ----
    {
        float acc[JPW];
#pragma unroll
        for (int jj = 0; jj < JPW; ++jj) acc[jj] = m.b2[j0 + jj];
#pragma unroll 16
        for (int k = 0; k < W; ++k) {
            float hk = hB[p * HSTR + k];
#pragma unroll
            for (int jj = 0; jj < JPW; ++jj)
                acc[jj] = fmaf(hk, m.w2T[k * W + j0 + jj], acc[jj]);
        }
#pragma unroll
        for (int jj = 0; jj < JPW; ++jj) hA[p * HSTR + j0 + jj] = ftanh(acc[jj]);
    }
    __syncthreads();
    // ---- L3: 64 -> 1 (slice-partial then reduce via LDS) ----
    float partial = 0.0f;
#pragma unroll
    for (int kk = 0; kk < JPW; ++kk)
        partial = fmaf(hA[p * HSTR + j0 + kk], m.w3[j0 + kk], partial);
    part[p * (SLICES + 1) + s] = partial;
    __syncthreads();
    float sum = m.b3;
#pragma unroll
    for (int ss = 0; ss < SLICES; ++ss) sum += part[p * (SLICES + 1) + ss];
    return sum;
}

__global__ __launch_bounds__(NT, 1) void sim_kernel(
    const float* __restrict__ init_var, const float* __restrict__ dtp,
    const float* __restrict__ dwg,
    const float* __restrict__ dW0, const float* __restrict__ dB0,
    const float* __restrict__ dW1, const float* __restrict__ dB1,
    const float* __restrict__ dW2, const float* __restrict__ dB2,
    const float* __restrict__ dW3, const float* __restrict__ dB3,
    const float* __restrict__ fW0, const float* __restrict__ fB0,
    const float* __restrict__ fW1, const float* __restrict__ fB1,
    const float* __restrict__ fW2, const float* __restrict__ fB2,
    const float* __restrict__ fW3, const float* __restrict__ fB3,
    float* __restrict__ out)
{
    extern __shared__ float smem[];
    float* w1Td = smem;               // 4096
    float* w2Td = w1Td + 4096;        // 4096
    float* w1Tf = w2Td + 4096;        // 4096
    float* w2Tf = w1Tf + 4096;        // 4096
    float* w0d  = w2Tf + 4096;        // 960
    float* w0f  = w0d + 960;          // 960
    float* bd   = w0f + 960;          // 256: b0|b1|b2|w3
    float* bf   = bd + 256;           // 256
    float* hA   = bf + 256;           // PPB*HSTR = 2080
    float* hB   = hA + PPB * HSTR;    // 2080
    float* part = hB + PPB * HSTR;    // PPB*9 = 288

    const int tid = threadIdx.x;

    // ---- cooperative weight staging (transpose w1/w2 for conflict-free reads) ----
    for (int i = tid; i < 4096; i += NT) {
        int j = i >> 6, k = i & 63;           // i = j*64 + k
        w1Td[k * W + j] = dW1[i];
        w2Td[k * W + j] = dW2[i];
        w1Tf[k * W + j] = fW1[i];
        w2Tf[k * W + j] = fW2[i];
    }
    for (int i = tid; i < 960; i += NT) { w0d[i] = dW0[i]; w0f[i] = fW0[i]; }
    if (tid < 64) {
        bd[tid]       = dB0[tid];
        bd[64 + tid]  = dB1[tid];
        bd[128 + tid] = dB2[tid];
        bd[192 + tid] = dW3[tid];
        bf[tid]       = fB0[tid];
        bf[64 + tid]  = fB1[tid];
        bf[128 + tid] = fB2[tid];
        bf[192 + tid] = fW3[tid];
    }
    __syncthreads();

    const MlpW md = {w0d, bd, w1Td, bd + 64, w2Td, bd + 128, bd + 192, dB3[0]};
    const MlpW mf = {w0f, bf, w1Tf, bf + 64, w2Tf, bf + 128, bf + 192, fB3[0]};

    const float dt = dtp[0];
    const int p = tid & (PPB - 1);
    const int s = tid >> 5;
    const int path = blockIdx.x * PPB + p;

    float iv = init_var[path];
    iv = fminf(fmaxf(iv, 0.01f), 1.5f);
    float lv = __logf(iv);
    float s1a0 = 0.f, s1a1 = 0.f;
    float s2a[4] = {0.f, 0.f, 0.f, 0.f};
    float s3a[8] = {0.f, 0.f, 0.f, 0.f, 0.f, 0.f, 0.f, 0.f};

    for (int t = 0; t < TSTEPS; ++t) {
        float x[15];
        x[0] = s1a0; x[1] = s1a1;
        x[2] = s2a[0]; x[3] = s2a[1]; x[4] = s2a[2]; x[5] = s2a[3];
#pragma unroll
        for (int i = 0; i < 8; ++i) x[6 + i] = s3a[i];
        x[14] = lv + 4.0f;

        float od = mlp_eval(x, md, hA, hB, part, p, s);
        float of = mlp_eval(x, mf, hA, hB, part, p, s);

        float drift_nn = 0.5f * ftanh(od);
        float diffu = 1.5f * fsigm(of) + 0.1f;
        float dwv = dwg[(size_t)path * TSTEPS + t];

        float lvn = lv + KAPPA * (THETA - lv) * dt + drift_nn * dt + diffu * dwv;
        lvn = fminf(fmaxf(lvn, -5.0f), 1.0f);
        float d = lvn - lv;

        // dx = {dt, d}; out_xx = outer(dx,dx) row-major
        float o0 = dt * dt, o1 = dt * d, o2 = d * dt, o3 = d * d;

        // s3 += outer(s2, dx)  [s3[a*2+j] += s2[a]*dx[j]]
        s3a[0] += s2a[0] * dt; s3a[1] += s2a[0] * d;
        s3a[2] += s2a[1] * dt; s3a[3] += s2a[1] * d;
        s3a[4] += s2a[2] * dt; s3a[5] += s2a[2] * d;
        s3a[6] += s2a[3] * dt; s3a[7] += s2a[3] * d;
        // s3 += outer(s1, 0.5*out_xx)  [s3[i*4+m] += s1[i]*0.5*o[m]]
        s3a[0] += s1a0 * 0.5f * o0; s3a[1] += s1a0 * 0.5f * o1;
        s3a[2] += s1a0 * 0.5f * o2; s3a[3] += s1a0 * 0.5f * o3;
        s3a[4] += s1a1 * 0.5f * o0; s3a[5] += s1a1 * 0.5f * o1;
        s3a[6] += s1a1 * 0.5f * o2; s3a[7] += s1a1 * 0.5f * o3;
        // s3 += outer(dx, out_xx)/6  [s3[i*4+m] += dx[i]*o[m]/6]
        const float c6 = 1.0f / 6.0f;
        s3a[0] += dt * o0 * c6; s3a[1] += dt * o1 * c6;
        s3a[2] += dt * o2 * c6; s3a[3] += dt * o3 * c6;
        s3a[4] += d * o0 * c6;  s3a[5] += d * o1 * c6;
        s3a[6] += d * o2 * c6;  s3a[7] += d * o3 * c6;
        // s2 += outer(s1, dx) + 0.5*out_xx
        s2a[0] += s1a0 * dt + 0.5f * o0; s2a[1] += s1a0 * d + 0.5f * o1;
        s2a[2] += s1a1 * dt + 0.5f * o2; s2a[3] += s1a1 * d + 0.5f * o3;
        // s1 += dx
        s1a0 += dt; s1a1 += d;

        if (s == 0) out[(size_t)path * TSTEPS + t] = __expf(lvn);
        lv = lvn;
    }
}

extern "C" void kernel_launch(void* const* d_in, const int* in_sizes, int n_in,
                              void* d_out, int out_size, void* d_ws, size_t ws_size,
                              hipStream_t stream) {
    const float* init_var = (const float*)d_in[0];
    const float* dtp      = (const float*)d_in[1];
    const float* dwg      = (const float*)d_in[2];
    const float* dW0 = (const float*)d_in[3];
    const float* dB0 = (const float*)d_in[4];
    const float* dW1 = (const float*)d_in[5];
    const float* dB1 = (const float*)d_in[6];
    const float* dW2 = (const float*)d_in[7];
    const float* dB2 = (const float*)d_in[8];
    const float* dW3 = (const float*)d_in[9];
    const float* dB3 = (const float*)d_in[10];
    const float* fW0 = (const float*)d_in[11];
    const float* fB0 = (const float*)d_in[12];
    const float* fW1 = (const float*)d_in[13];
    const float* fB1 = (const float*)d_in[14];
    const float* fW2 = (const float*)d_in[15];
    const float* fB2 = (const float*)d_in[16];
    const float* fW3 = (const float*)d_in[17];
    const float* fB3 = (const float*)d_in[18];
    float* out = (float*)d_out;

    const size_t smem_bytes =
        (size_t)(4 * 4096 + 2 * 960 + 2 * 256 + 2 * PPB * HSTR + PPB * 9) * sizeof(float);

    hipFuncSetAttribute((const void*)sim_kernel,
                        hipFuncAttributeMaxDynamicSharedMemorySize, (int)smem_bytes);

    sim_kernel<<<dim3(BPATHS / PPB), dim3(NT), smem_bytes, stream>>>(
        init_var, dtp, dwg,
        dW0, dB0, dW1, dB1, dW2, dB2, dW3, dB3,
        fW0, fB0, fW1, fB1, fW2, fB2, fW3, fB3,
        out);
}

// Round 2
// 5965.251 us; speedup vs baseline: 12.4085x; 12.4085x over previous
//
#include <hip/hip_runtime.h>

#define TSTEPS 2048
#define PPB 32          // paths per block
#define NT 512          // 8 waves: Mt = w&1 (2 M-tiles), Nt = w>>1 (4 N-tiles)
#define XSTR 36         // x row stride (floats): 32 data cols (15 real + zero pad) + 4 pad
#define HSTR 68         // h row stride (floats): 64 data + 4 pad

#define KAPPA 2.72f
#define THETA -3.5f

typedef _Float16 half8 __attribute__((ext_vector_type(8)));
typedef float f32x4 __attribute__((ext_vector_type(4)));

__device__ __forceinline__ float ftanh(float x) {
    float e = __expf(2.0f * x);
    return 1.0f - 2.0f * __builtin_amdgcn_rcpf(e + 1.0f);
}
__device__ __forceinline__ float fsigm(float x) {
    return __builtin_amdgcn_rcpf(1.0f + __expf(-x));
}

__device__ __forceinline__ f32x4 mm(half8 a, half8 b, f32x4 c) {
    return __builtin_amdgcn_mfma_f32_16x16x32_f16(a, b, c, 0, 0, 0);
}

// Load 8 consecutive f32 from an LDS row, split into hi/lo fp16 fragments.
__device__ __forceinline__ void load_afrag(const float* row, int k0, half8& hi, half8& lo) {
    const f32x4 a = *(const f32x4*)(row + k0);
    const f32x4 b = *(const f32x4*)(row + k0 + 4);
#pragma unroll
    for (int i = 0; i < 4; ++i) {
        float f = a[i]; _Float16 h = (_Float16)f;
        hi[i] = h; lo[i] = (_Float16)(f - (float)h);
        float g = b[i]; _Float16 h2 = (_Float16)g;
        hi[4 + i] = h2; lo[4 + i] = (_Float16)(g - (float)h2);
    }
}

// Split one f32 weight into hi/lo fp16 pair.
__device__ __forceinline__ void wsplit(float v, _Float16& h, _Float16& l) {
    h = (_Float16)v; l = (_Float16)(v - (float)h);
}

__global__ __launch_bounds__(NT, 2) void sim_kernel(
    const float* __restrict__ init_var, const float* __restrict__ dtp,
    const float* __restrict__ dwg,
    const float* __restrict__ dW0, const float* __restrict__ dB0,
    const float* __restrict__ dW1, const float* __restrict__ dB1,
    const float* __restrict__ dW2, const float* __restrict__ dB2,
    const float* __restrict__ dW3, const float* __restrict__ dB3,
    const float* __restrict__ fW0, const float* __restrict__ fB0,
    const float* __restrict__ fW1, const float* __restrict__ fB1,
    const float* __restrict__ fW2, const float* __restrict__ fB2,
    const float* __restrict__ fW3, const float* __restrict__ fB3,
    float* __restrict__ out)
{
    __shared__ __align__(16) float xL[PPB * XSTR];
    __shared__ __align__(16) float hAd[PPB * HSTR];
    __shared__ __align__(16) float hAf[PPB * HSTR];
    __shared__ __align__(16) float hBd[PPB * HSTR];
    __shared__ __align__(16) float hBf[PPB * HSTR];
    __shared__ __align__(16) float part_d[PPB * 4];
    __shared__ __align__(16) float part_f[PPB * 4];

    const int tid  = threadIdx.x;
    const int lane = tid & 63;
    const int w    = tid >> 6;       // wave 0..7
    const int Mt   = w & 1;
    const int Nt   = w >> 1;         // 0..3
    const int l15  = lane & 15;
    const int lg   = lane >> 4;      // 0..3
    const int col  = Nt * 16 + l15;  // output column this lane supplies (B) / owns (C)
    const int arow = Mt * 16 + l15;  // A-fragment row (path index within block)
    const int crow0 = Mt * 16 + lg * 4;  // first C row this lane owns

    // ---------------- startup: B-fragments (hi/lo fp16) into registers ----------------
    // B[k][n] = W[n][k] for row-major W[out][in]. Lane supplies col=n, k = kp*32 + lg*8 + i.
    half8 bd0h, bd0l, bf0h, bf0l;
    {
        const int k0 = lg * 8;
#pragma unroll
        for (int i = 0; i < 8; ++i) {
            const int k = k0 + i;
            float vd = (k < 15) ? dW0[col * 15 + k] : 0.f;
            float vf = (k < 15) ? fW0[col * 15 + k] : 0.f;
            _Float16 h, l;
            wsplit(vd, h, l); bd0h[i] = h; bd0l[i] = l;
            wsplit(vf, h, l); bf0h[i] = h; bf0l[i] = l;
        }
    }
    half8 bd1h0, bd1l0, bd1h1, bd1l1, bd2h0, bd2l0, bd2h1, bd2l1;
    half8 bf1h0, bf1l0, bf1h1, bf1l1, bf2h0, bf2l0, bf2h1, bf2l1;
    {
        const int ka = lg * 8, kb = 32 + lg * 8;
#pragma unroll
        for (int i = 0; i < 8; ++i) {
            _Float16 h, l;
            wsplit(dW1[col * 64 + ka + i], h, l); bd1h0[i] = h; bd1l0[i] = l;
            wsplit(dW1[col * 64 + kb + i], h, l); bd1h1[i] = h; bd1l1[i] = l;
            wsplit(dW2[col * 64 + ka + i], h, l); bd2h0[i] = h; bd2l0[i] = l;
            wsplit(dW2[col * 64 + kb + i], h, l); bd2h1[i] = h; bd2l1[i] = l;
            wsplit(fW1[col * 64 + ka + i], h, l); bf1h0[i] = h; bf1l0[i] = l;
            wsplit(fW1[col * 64 + kb + i], h, l); bf1h1[i] = h; bf1l1[i] = l;
            wsplit(fW2[col * 64 + ka + i], h, l); bf2h0[i] = h; bf2l0[i] = l;
            wsplit(fW2[col * 64 + kb + i], h, l); bf2h1[i] = h; bf2l1[i] = l;
        }
    }
    const float biasd0 = dB0[col], biasd1 = dB1[col], biasd2 = dB2[col];
    const float biasf0 = fB0[col], biasf1 = fB1[col], biasf2 = fB2[col];
    const float w3d = dW3[col], w3f = fW3[col];
    const float b3d = dB3[0],  b3f = fB3[0];
    const float dt  = dtp[0];

    // ---------------- state init ----------------
    const int p    = tid & 31;
    const int path = blockIdx.x * PPB + p;
    float lv = 0.f;
    float s1a0 = 0.f, s1a1 = 0.f;
    float s2a0 = 0.f, s2a1 = 0.f, s2a2 = 0.f, s2a3 = 0.f;
    float s3a0 = 0.f, s3a1 = 0.f, s3a2 = 0.f, s3a3 = 0.f;
    float s3a4 = 0.f, s3a5 = 0.f, s3a6 = 0.f, s3a7 = 0.f;
    if (tid < 32) {
        float iv = fminf(fmaxf(init_var[path], 0.01f), 1.5f);
        lv = __logf(iv);
    }
    for (int i = tid; i < PPB * XSTR; i += NT) xL[i] = 0.f;
    __syncthreads();
    if (tid < 32) xL[p * XSTR + 14] = lv + 4.0f;
    __syncthreads();

    for (int t = 0; t < TSTEPS; ++t) {
        float dwv = 0.f;
        if (tid < 32) dwv = dwg[(size_t)path * TSTEPS + t];

        // ---- L0: x(K=32, zero-padded past 14) -> h0 ----
        {
            half8 axh, axl;
            load_afrag(xL + arow * XSTR, lg * 8, axh, axl);
            f32x4 cd = {biasd0, biasd0, biasd0, biasd0};
            f32x4 cf = {biasf0, biasf0, biasf0, biasf0};
            cd = mm(axh, bd0h, cd);  cf = mm(axh, bf0h, cf);
            cd = mm(axh, bd0l, cd);  cf = mm(axh, bf0l, cf);
            cd = mm(axl, bd0h, cd);  cf = mm(axl, bf0h, cf);
#pragma unroll
            for (int r = 0; r < 4; ++r) {
                hAd[(crow0 + r) * HSTR + col] = ftanh(cd[r]);
                hAf[(crow0 + r) * HSTR + col] = ftanh(cf[r]);
            }
        }
        __syncthreads();

        // ---- L1: h0 -> h1 ----
        {
            half8 ad0h, ad0l, ad1h, ad1l, af0h, af0l, af1h, af1l;
            load_afrag(hAd + arow * HSTR,      lg * 8, ad0h, ad0l);
            load_afrag(hAd + arow * HSTR, 32 + lg * 8, ad1h, ad1l);
            load_afrag(hAf + arow * HSTR,      lg * 8, af0h, af0l);
            load_afrag(hAf + arow * HSTR, 32 + lg * 8, af1h, af1l);
            f32x4 cd = {biasd1, biasd1, biasd1, biasd1};
            f32x4 cf = {biasf1, biasf1, biasf1, biasf1};
            cd = mm(ad0h, bd1h0, cd);  cf = mm(af0h, bf1h0, cf);
            cd = mm(ad0h, bd1l0, cd);  cf = mm(af0h, bf1l0, cf);
            cd = mm(ad0l, bd1h0, cd);  cf = mm(af0l, bf1h0, cf);
            cd = mm(ad1h, bd1h1, cd);  cf = mm(af1h, bf1h1, cf);
            cd = mm(ad1h, bd1l1, cd);  cf = mm(af1h, bf1l1, cf);
            cd = mm(ad1l, bd1h1, cd);  cf = mm(af1l, bf1h1, cf);
#pragma unroll
            for (int r = 0; r < 4; ++r) {
                hBd[(crow0 + r) * HSTR + col] = ftanh(cd[r]);
                hBf[(crow0 + r) * HSTR + col] = ftanh(cf[r]);
            }
        }
        __syncthreads();

        // ---- L2: h1 -> h2, fused L3 partial (out = h2 . w3) ----
        {
            half8 ad0h, ad0l, ad1h, ad1l, af0h, af0l, af1h, af1l;
            load_afrag(hBd + arow * HSTR,      lg * 8, ad0h, ad0l);
            load_afrag(hBd + arow * HSTR, 32 + lg * 8, ad1h, ad1l);
            load_afrag(hBf + arow * HSTR,      lg * 8, af0h, af0l);
            load_afrag(hBf + arow * HSTR, 32 + lg * 8, af1h, af1l);
            f32x4 cd = {biasd2, biasd2, biasd2, biasd2};
            f32x4 cf = {biasf2, biasf2, biasf2, biasf2};
            cd = mm(ad0h, bd2h0, cd);  cf = mm(af0h, bf2h0, cf);
            cd = mm(ad0h, bd2l0, cd);  cf = mm(af0h, bf2l0, cf);
            cd = mm(ad0l, bd2h0, cd);  cf = mm(af0l, bf2h0, cf);
            cd = mm(ad1h, bd2h1, cd);  cf = mm(af1h, bf2h1, cf);
            cd = mm(ad1h, bd2l1, cd);  cf = mm(af1h, bf2l1, cf);
            cd = mm(ad1l, bd2h1, cd);  cf = mm(af1l, bf2h1, cf);
            float prd0 = ftanh(cd[0]) * w3d, prd1 = ftanh(cd[1]) * w3d;
            float prd2 = ftanh(cd[2]) * w3d, prd3 = ftanh(cd[3]) * w3d;
            float prf0 = ftanh(cf[0]) * w3f, prf1 = ftanh(cf[1]) * w3f;
            float prf2 = ftanh(cf[2]) * w3f, prf3 = ftanh(cf[3]) * w3f;
#pragma unroll
            for (int m = 1; m <= 8; m <<= 1) {
                prd0 += __shfl_xor(prd0, m); prd1 += __shfl_xor(prd1, m);
                prd2 += __shfl_xor(prd2, m); prd3 += __shfl_xor(prd3, m);
                prf0 += __shfl_xor(prf0, m); prf1 += __shfl_xor(prf1, m);
                prf2 += __shfl_xor(prf2, m); prf3 += __shfl_xor(prf3, m);
            }
            if (l15 == 0) {
                part_d[(crow0 + 0) * 4 + Nt] = prd0;
                part_d[(crow0 + 1) * 4 + Nt] = prd1;
                part_d[(crow0 + 2) * 4 + Nt] = prd2;
                part_d[(crow0 + 3) * 4 + Nt] = prd3;
                part_f[(crow0 + 0) * 4 + Nt] = prf0;
                part_f[(crow0 + 1) * 4 + Nt] = prf1;
                part_f[(crow0 + 2) * 4 + Nt] = prf2;
                part_f[(crow0 + 3) * 4 + Nt] = prf3;
            }
        }
        __syncthreads();

        // ---- state update (wave 0: lanes 0-31 drift sum, lanes 32-63 diff sum) ----
        float sum4 = 0.f;
        if (tid < 64) {
            const float* pp = (tid < 32) ? part_d : part_f;
            f32x4 v = *(const f32x4*)(pp + (tid & 31) * 4);
            sum4 = v[0] + v[1] + v[2] + v[3] + ((tid < 32) ? b3d : b3f);
        }
        float other = __shfl_xor(sum4, 32);
        if (tid < 32) {
            const float od = sum4, of = other;
            const float drift_nn = 0.5f * ftanh(od);
            const float diffu = 1.5f * fsigm(of) + 0.1f;
            float lvn = lv + KAPPA * (THETA - lv) * dt + drift_nn * dt + diffu * dwv;
            lvn = fminf(fmaxf(lvn, -5.0f), 1.0f);
            const float d = lvn - lv;
            const float o0 = dt * dt, o1 = dt * d, o2 = d * dt, o3 = d * d;
            const float c6 = 1.0f / 6.0f;
            // s3 += outer(s2,dx) + outer(s1,0.5*oxx) + outer(dx,oxx)/6
            s3a0 += s2a0 * dt + s1a0 * 0.5f * o0 + dt * o0 * c6;
            s3a1 += s2a0 * d  + s1a0 * 0.5f * o1 + dt * o1 * c6;
            s3a2 += s2a1 * dt + s1a0 * 0.5f * o2 + dt * o2 * c6;
            s3a3 += s2a1 * d  + s1a0 * 0.5f * o3 + dt * o3 * c6;
            s3a4 += s2a2 * dt + s1a1 * 0.5f * o0 + d * o0 * c6;
            s3a5 += s2a2 * d  + s1a1 * 0.5f * o1 + d * o1 * c6;
            s3a6 += s2a3 * dt + s1a1 * 0.5f * o2 + d * o2 * c6;
            s3a7 += s2a3 * d  + s1a1 * 0.5f * o3 + d * o3 * c6;
            // s2 += outer(s1,dx) + 0.5*oxx
            s2a0 += s1a0 * dt + 0.5f * o0;  s2a1 += s1a0 * d + 0.5f * o1;
            s2a2 += s1a1 * dt + 0.5f * o2;  s2a3 += s1a1 * d + 0.5f * o3;
            // s1 += dx
            s1a0 += dt;  s1a1 += d;
            out[(size_t)path * TSTEPS + t] = __expf(lvn);
            lv = lvn;
            f32x4 x0 = {s1a0, s1a1, s2a0, s2a1};
            f32x4 x1 = {s2a2, s2a3, s3a0, s3a1};
            f32x4 x2 = {s3a2, s3a3, s3a4, s3a5};
            f32x4 x3 = {s3a6, s3a7, lv + 4.0f, 0.f};
            *(f32x4*)(xL + p * XSTR + 0)  = x0;
            *(f32x4*)(xL + p * XSTR + 4)  = x1;
            *(f32x4*)(xL + p * XSTR + 8)  = x2;
            *(f32x4*)(xL + p * XSTR + 12) = x3;
        }
        __syncthreads();
    }
}

extern "C" void kernel_launch(void* const* d_in, const int* in_sizes, int n_in,
                              void* d_out, int out_size, void* d_ws, size_t ws_size,
                              hipStream_t stream) {
    const float* init_var = (const float*)d_in[0];
    const float* dtp      = (const float*)d_in[1];
    const float* dwg      = (const float*)d_in[2];
    const float* dW0 = (const float*)d_in[3];
    const float* dB0 = (const float*)d_in[4];
    const float* dW1 = (const float*)d_in[5];
    const float* dB1 = (const float*)d_in[6];
    const float* dW2 = (const float*)d_in[7];
    const float* dB2 = (const float*)d_in[8];
    const float* dW3 = (const float*)d_in[9];
    const float* dB3 = (const float*)d_in[10];
    const float* fW0 = (const float*)d_in[11];
    const float* fB0 = (const float*)d_in[12];
    const float* fW1 = (const float*)d_in[13];
    const float* fB1 = (const float*)d_in[14];
    const float* fW2 = (const float*)d_in[15];
    const float* fB2 = (const float*)d_in[16];
    const float* fW3 = (const float*)d_in[17];
    const float* fB3 = (const float*)d_in[18];
    float* out = (float*)d_out;

    sim_kernel<<<dim3(8192 / PPB), dim3(NT), 0, stream>>>(
        init_var, dtp, dwg,
        dW0, dB0, dW1, dB1, dW2, dB2, dW3, dB3,
        fW0, fB0, fW1, fB1, fW2, fB2, fW3, fB3,
        out);
}

// Round 3
// 4771.819 us; speedup vs baseline: 15.5119x; 1.2501x over previous
//
#include <hip/hip_runtime.h>

#define TSTEPS 2048
#define PPB 16          // paths per block
#define NT 256          // 4 waves; wave w = Nt (column tile), handles BOTH MLPs
#define KAPPA 2.72f
#define THETA -3.5f

typedef _Float16 half8 __attribute__((ext_vector_type(8)));
typedef float f32x4 __attribute__((ext_vector_type(4)));

__device__ __forceinline__ float ftanh(float x) {
    float e = __expf(2.0f * x);
    return 1.0f - 2.0f * __builtin_amdgcn_rcpf(e + 1.0f);
}
__device__ __forceinline__ float fsigm(float x) {
    return __builtin_amdgcn_rcpf(1.0f + __expf(-x));
}
__device__ __forceinline__ f32x4 mm(half8 a, half8 b, f32x4 c) {
    return __builtin_amdgcn_mfma_f32_16x16x32_f16(a, b, c, 0, 0, 0);
}
__device__ __forceinline__ void wsplit(float v, _Float16& h, _Float16& l) {
    h = (_Float16)v; l = (_Float16)(v - (float)h);
}

// LDS activation layout (f16): [row 0..15][chunk-slot 0..7][elem 0..7],
// slot = (k>>3) ^ (row & 7)  -> conflict-free b128 A-fragment reads.

__global__ __launch_bounds__(NT, 2) void sim_kernel(
    const float* __restrict__ init_var, const float* __restrict__ dtp,
    const float* __restrict__ dwg,
    const float* __restrict__ dW0, const float* __restrict__ dB0,
    const float* __restrict__ dW1, const float* __restrict__ dB1,
    const float* __restrict__ dW2, const float* __restrict__ dB2,
    const float* __restrict__ dW3, const float* __restrict__ dB3,
    const float* __restrict__ fW0, const float* __restrict__ fB0,
    const float* __restrict__ fW1, const float* __restrict__ fB1,
    const float* __restrict__ fW2, const float* __restrict__ fB2,
    const float* __restrict__ fW3, const float* __restrict__ fB3,
    float* __restrict__ out)
{
    __shared__ __align__(16) _Float16 xhi[PPB * 64];
    __shared__ __align__(16) _Float16 xlo[PPB * 64];
    __shared__ __align__(16) _Float16 hAd[PPB * 64];
    __shared__ __align__(16) _Float16 hAf[PPB * 64];
    __shared__ __align__(16) _Float16 hBd[PPB * 64];
    __shared__ __align__(16) _Float16 hBf[PPB * 64];
    __shared__ __align__(16) float part_d[PPB * 4];
    __shared__ __align__(16) float part_f[PPB * 4];

    const int tid  = threadIdx.x;
    const int lane = tid & 63;
    const int Nt   = tid >> 6;        // wave index 0..3 = column tile
    const int l15  = lane & 15;
    const int lg   = lane >> 4;       // 0..3
    const int col  = Nt * 16 + l15;   // B column this lane supplies / C column it owns
    const int q    = l15 & 7;

    // A-fragment read offsets (f16 elements), swizzled; loop-invariant.
    const int roff0 = l15 * 64 + ((lg ^ q) << 3);          // k-slice 0 (chunks 0-3)
    const int roff1 = l15 * 64 + (((4 + lg) ^ q) << 3);    // k-slice 1 (chunks 4-7)
    // C write offsets: row = lg*4+r, k-position = col.
    int woff[4];
#pragma unroll
    for (int r = 0; r < 4; ++r) {
        const int wrow = lg * 4 + r;
        woff[r] = wrow * 64 + ((((col >> 3) ^ (wrow & 7))) << 3) + (col & 7);
    }

    // ---------------- startup: B-fragments (hi/lo f16) into registers ----------------
    half8 bd0h, bd0l, bf0h, bf0l;
#pragma unroll
    for (int i = 0; i < 8; ++i) {
        const int k = lg * 8 + i;
        float vd = (k < 15) ? dW0[col * 15 + k] : 0.f;
        float vf = (k < 15) ? fW0[col * 15 + k] : 0.f;
        _Float16 h, l;
        wsplit(vd, h, l); bd0h[i] = h; bd0l[i] = l;
        wsplit(vf, h, l); bf0h[i] = h; bf0l[i] = l;
    }
    half8 bd1h0, bd1l0, bd1h1, bd1l1, bd2h0, bd2l0, bd2h1, bd2l1;
    half8 bf1h0, bf1l0, bf1h1, bf1l1, bf2h0, bf2l0, bf2h1, bf2l1;
#pragma unroll
    for (int i = 0; i < 8; ++i) {
        const int ka = lg * 8 + i, kb = 32 + lg * 8 + i;
        _Float16 h, l;
        wsplit(dW1[col * 64 + ka], h, l); bd1h0[i] = h; bd1l0[i] = l;
        wsplit(dW1[col * 64 + kb], h, l); bd1h1[i] = h; bd1l1[i] = l;
        wsplit(dW2[col * 64 + ka], h, l); bd2h0[i] = h; bd2l0[i] = l;
        wsplit(dW2[col * 64 + kb], h, l); bd2h1[i] = h; bd2l1[i] = l;
        wsplit(fW1[col * 64 + ka], h, l); bf1h0[i] = h; bf1l0[i] = l;
        wsplit(fW1[col * 64 + kb], h, l); bf1h1[i] = h; bf1l1[i] = l;
        wsplit(fW2[col * 64 + ka], h, l); bf2h0[i] = h; bf2l0[i] = l;
        wsplit(fW2[col * 64 + kb], h, l); bf2h1[i] = h; bf2l1[i] = l;
    }
    const float biasd0 = dB0[col], biasd1 = dB1[col], biasd2 = dB2[col];
    const float biasf0 = fB0[col], biasf1 = fB1[col], biasf2 = fB2[col];
    const float w3d = dW3[col], w3f = fW3[col];
    const float b3d = dB3[0],  b3f = fB3[0];
    const float dt  = dtp[0];

    // ---------------- state init ----------------
    const int p = tid & 15;
    const int path = blockIdx.x * PPB + p;
    const size_t pathT = (size_t)path * TSTEPS;
    float lv = 0.f;
    float s1a0 = 0.f, s1a1 = 0.f;
    float s2a0 = 0.f, s2a1 = 0.f, s2a2 = 0.f, s2a3 = 0.f;
    float s3a0 = 0.f, s3a1 = 0.f, s3a2 = 0.f, s3a3 = 0.f;
    float s3a4 = 0.f, s3a5 = 0.f, s3a6 = 0.f, s3a7 = 0.f;
    if (tid < PPB) {
        float iv = fminf(fmaxf(init_var[path], 0.01f), 1.5f);
        lv = __logf(iv);
    }
    for (int i = tid; i < PPB * 64; i += NT) { xhi[i] = (_Float16)0.f; xlo[i] = (_Float16)0.f; }
    __syncthreads();
    if (tid < PPB) {
        // x[14] = lv + 4 lives in chunk 1, elem 6; chunk1 slot = 1 ^ (p&7)
        const int o = p * 64 + ((1 ^ (p & 7)) << 3) + 6;
        _Float16 h, l; wsplit(lv + 4.0f, h, l);
        xhi[o] = h; xlo[o] = l;
    }
    __syncthreads();

    const int xw0 = p * 64 + ((0 ^ (p & 7)) << 3);   // chunk0 write offset
    const int xw1 = p * 64 + ((1 ^ (p & 7)) << 3);   // chunk1 write offset

    for (int t = 0; t < TSTEPS; ++t) {
        float dwv = 0.f;
        if (tid < PPB) dwv = dwg[pathT + t];

        // ---- L0: x (K=32, chunks 2-7 zero) -> h0 ; 3-term for x ----
        {
            const half8 axh = *(const half8*)(xhi + roff0);
            const half8 axl = *(const half8*)(xlo + roff0);
            f32x4 cd = {biasd0, biasd0, biasd0, biasd0};
            f32x4 cf = {biasf0, biasf0, biasf0, biasf0};
            cd = mm(axh, bd0h, cd);  cf = mm(axh, bf0h, cf);
            cd = mm(axh, bd0l, cd);  cf = mm(axh, bf0l, cf);
            cd = mm(axl, bd0h, cd);  cf = mm(axl, bf0h, cf);
#pragma unroll
            for (int r = 0; r < 4; ++r) {
                hAd[woff[r]] = (_Float16)ftanh(cd[r]);
                hAf[woff[r]] = (_Float16)ftanh(cf[r]);
            }
        }
        __syncthreads();

        // ---- L1: h0 -> h1 (A = f16 acts, hi-only; B = hi+lo) ----
        {
            const half8 ad0 = *(const half8*)(hAd + roff0);
            const half8 ad1 = *(const half8*)(hAd + roff1);
            const half8 af0 = *(const half8*)(hAf + roff0);
            const half8 af1 = *(const half8*)(hAf + roff1);
            f32x4 cd = {biasd1, biasd1, biasd1, biasd1};
            f32x4 cf = {biasf1, biasf1, biasf1, biasf1};
            cd = mm(ad0, bd1h0, cd);  cf = mm(af0, bf1h0, cf);
            cd = mm(ad0, bd1l0, cd);  cf = mm(af0, bf1l0, cf);
            cd = mm(ad1, bd1h1, cd);  cf = mm(af1, bf1h1, cf);
            cd = mm(ad1, bd1l1, cd);  cf = mm(af1, bf1l1, cf);
#pragma unroll
            for (int r = 0; r < 4; ++r) {
                hBd[woff[r]] = (_Float16)ftanh(cd[r]);
                hBf[woff[r]] = (_Float16)ftanh(cf[r]);
            }
        }
        __syncthreads();

        // ---- L2: h1 -> h2, fused L3 partial ----
        {
            const half8 ad0 = *(const half8*)(hBd + roff0);
            const half8 ad1 = *(const half8*)(hBd + roff1);
            const half8 af0 = *(const half8*)(hBf + roff0);
            const half8 af1 = *(const half8*)(hBf + roff1);
            f32x4 cd = {biasd2, biasd2, biasd2, biasd2};
            f32x4 cf = {biasf2, biasf2, biasf2, biasf2};
            cd = mm(ad0, bd2h0, cd);  cf = mm(af0, bf2h0, cf);
            cd = mm(ad0, bd2l0, cd);  cf = mm(af0, bf2l0, cf);
            cd = mm(ad1, bd2h1, cd);  cf = mm(af1, bf2h1, cf);
            cd = mm(ad1, bd2l1, cd);  cf = mm(af1, bf2l1, cf);
            float prd0 = ftanh(cd[0]) * w3d, prd1 = ftanh(cd[1]) * w3d;
            float prd2 = ftanh(cd[2]) * w3d, prd3 = ftanh(cd[3]) * w3d;
            float prf0 = ftanh(cf[0]) * w3f, prf1 = ftanh(cf[1]) * w3f;
            float prf2 = ftanh(cf[2]) * w3f, prf3 = ftanh(cf[3]) * w3f;
#pragma unroll
            for (int m = 1; m <= 8; m <<= 1) {
                prd0 += __shfl_xor(prd0, m); prd1 += __shfl_xor(prd1, m);
                prd2 += __shfl_xor(prd2, m); prd3 += __shfl_xor(prd3, m);
                prf0 += __shfl_xor(prf0, m); prf1 += __shfl_xor(prf1, m);
                prf2 += __shfl_xor(prf2, m); prf3 += __shfl_xor(prf3, m);
            }
            if (l15 == 0) {
                const int cr = lg * 4;
                part_d[(cr + 0) * 4 + Nt] = prd0;
                part_d[(cr + 1) * 4 + Nt] = prd1;
                part_d[(cr + 2) * 4 + Nt] = prd2;
                part_d[(cr + 3) * 4 + Nt] = prd3;
                part_f[(cr + 0) * 4 + Nt] = prf0;
                part_f[(cr + 1) * 4 + Nt] = prf1;
                part_f[(cr + 2) * 4 + Nt] = prf2;
                part_f[(cr + 3) * 4 + Nt] = prf3;
            }
        }
        __syncthreads();

        // ---- state update: lanes 0-15 (drift) + 16-31 (diff) of wave 0 ----
        float sum4 = 0.f;
        if (tid < 32) {
            const float* pp = (tid < PPB) ? part_d : part_f;
            f32x4 v = *(const f32x4*)(pp + (tid & 15) * 4);
            sum4 = v[0] + v[1] + v[2] + v[3] + ((tid < PPB) ? b3d : b3f);
        }
        float other = __shfl_xor(sum4, 16);
        if (tid < PPB) {
            const float od = sum4, of = other;
            const float drift_nn = 0.5f * ftanh(od);
            const float diffu = 1.5f * fsigm(of) + 0.1f;
            float lvn = lv + KAPPA * (THETA - lv) * dt + drift_nn * dt + diffu * dwv;
            lvn = fminf(fmaxf(lvn, -5.0f), 1.0f);
            const float d = lvn - lv;
            const float o0 = dt * dt, o1 = dt * d, o2 = d * dt, o3 = d * d;
            const float c6 = 1.0f / 6.0f;
            s3a0 += s2a0 * dt + s1a0 * 0.5f * o0 + dt * o0 * c6;
            s3a1 += s2a0 * d  + s1a0 * 0.5f * o1 + dt * o1 * c6;
            s3a2 += s2a1 * dt + s1a0 * 0.5f * o2 + dt * o2 * c6;
            s3a3 += s2a1 * d  + s1a0 * 0.5f * o3 + dt * o3 * c6;
            s3a4 += s2a2 * dt + s1a1 * 0.5f * o0 + d * o0 * c6;
            s3a5 += s2a2 * d  + s1a1 * 0.5f * o1 + d * o1 * c6;
            s3a6 += s2a3 * dt + s1a1 * 0.5f * o2 + d * o2 * c6;
            s3a7 += s2a3 * d  + s1a1 * 0.5f * o3 + d * o3 * c6;
            s2a0 += s1a0 * dt + 0.5f * o0;  s2a1 += s1a0 * d + 0.5f * o1;
            s2a2 += s1a1 * dt + 0.5f * o2;  s2a3 += s1a1 * d + 0.5f * o3;
            s1a0 += dt;  s1a1 += d;
            out[pathT + t] = __expf(lvn);
            lv = lvn;

            // write next x (split hi/lo f16), chunk0 = {s1,s2,s3[0:2]}, chunk1 = {s3[2:8], x14, 0}
            float c0v[8] = {s1a0, s1a1, s2a0, s2a1, s2a2, s2a3, s3a0, s3a1};
            float c1v[8] = {s3a2, s3a3, s3a4, s3a5, s3a6, s3a7, lv + 4.0f, 0.f};
            half8 c0h, c0l, c1h, c1l;
#pragma unroll
            for (int i = 0; i < 8; ++i) {
                _Float16 h, l;
                wsplit(c0v[i], h, l); c0h[i] = h; c0l[i] = l;
                wsplit(c1v[i], h, l); c1h[i] = h; c1l[i] = l;
            }
            *(half8*)(xhi + xw0) = c0h;  *(half8*)(xlo + xw0) = c0l;
            *(half8*)(xhi + xw1) = c1h;  *(half8*)(xlo + xw1) = c1l;
        }
        __syncthreads();
    }
}

extern "C" void kernel_launch(void* const* d_in, const int* in_sizes, int n_in,
                              void* d_out, int out_size, void* d_ws, size_t ws_size,
                              hipStream_t stream) {
    const float* init_var = (const float*)d_in[0];
    const float* dtp      = (const float*)d_in[1];
    const float* dwg      = (const float*)d_in[2];
    const float* dW0 = (const float*)d_in[3];
    const float* dB0 = (const float*)d_in[4];
    const float* dW1 = (const float*)d_in[5];
    const float* dB1 = (const float*)d_in[6];
    const float* dW2 = (const float*)d_in[7];
    const float* dB2 = (const float*)d_in[8];
    const float* dW3 = (const float*)d_in[9];
    const float* dB3 = (const float*)d_in[10];
    const float* fW0 = (const float*)d_in[11];
    const float* fB0 = (const float*)d_in[12];
    const float* fW1 = (const float*)d_in[13];
    const float* fB1 = (const float*)d_in[14];
    const float* fW2 = (const float*)d_in[15];
    const float* fB2 = (const float*)d_in[16];
    const float* fW3 = (const float*)d_in[17];
    const float* fB3 = (const float*)d_in[18];
    float* out = (float*)d_out;

    sim_kernel<<<dim3(8192 / PPB), dim3(NT), 0, stream>>>(
        init_var, dtp, dwg,
        dW0, dB0, dW1, dB1, dW2, dB2, dW3, dB3,
        fW0, fB0, fW1, fB1, fW2, fB2, fW3, fB3,
        out);
}

// Round 4
// 4155.746 us; speedup vs baseline: 17.8115x; 1.1482x over previous
//
#include <hip/hip_runtime.h>

#define TSTEPS 2048
#define PPB 16          // paths per block
#define NT 256          // 4 waves; wave wv = N-tile (16 cols of both MLPs)
#define KAPPA 2.72f
#define THETA -3.5f

typedef _Float16 half8 __attribute__((ext_vector_type(8)));
typedef float f32x4 __attribute__((ext_vector_type(4)));

__device__ __forceinline__ float ftanh(float x) {
    float e = __expf(2.0f * x);
    return 1.0f - 2.0f * __builtin_amdgcn_rcpf(e + 1.0f);
}
__device__ __forceinline__ float fsigm(float x) {
    return __builtin_amdgcn_rcpf(1.0f + __expf(-x));
}
__device__ __forceinline__ f32x4 mm(half8 a, half8 b, f32x4 c) {
    return __builtin_amdgcn_mfma_f32_16x16x32_f16(a, b, c, 0, 0, 0);
}
__device__ __forceinline__ void wsplit(float v, _Float16& h, _Float16& l) {
    h = (_Float16)v; l = (_Float16)(v - (float)h);
}

// LDS f16 activation rows: [row 0..15][slot 0..7][elem 0..7], slot = chunk ^ (row&7).
// x buffer is per-wave-private, packed: K 0..15 = x_hi, K 16..31 = x_lo.

__global__ __launch_bounds__(NT, 2) void sim_kernel(
    const float* __restrict__ init_var, const float* __restrict__ dtp,
    const float* __restrict__ dwg,
    const float* __restrict__ dW0, const float* __restrict__ dB0,
    const float* __restrict__ dW1, const float* __restrict__ dB1,
    const float* __restrict__ dW2, const float* __restrict__ dB2,
    const float* __restrict__ dW3, const float* __restrict__ dB3,
    const float* __restrict__ fW0, const float* __restrict__ fB0,
    const float* __restrict__ fW1, const float* __restrict__ fB1,
    const float* __restrict__ fW2, const float* __restrict__ fB2,
    const float* __restrict__ fW3, const float* __restrict__ fB3,
    float* __restrict__ out)
{
    __shared__ __align__(16) _Float16 hAd[1024], hAf[1024];
    __shared__ __align__(16) _Float16 hBd[1024], hBf[1024];
    __shared__ __align__(16) _Float16 hCd[1024], hCf[1024];
    __shared__ __align__(16) _Float16 xpk[4][1024];

    const int tid  = threadIdx.x;
    const int lane = tid & 63;
    const int wv   = tid >> 6;        // wave index 0..3 = column tile
    const int l15  = lane & 15;
    const int lg   = lane >> 4;       // 0..3
    const int col  = wv * 16 + l15;   // B column this lane supplies / C column it owns
    const int q    = l15 & 7;

    const int roff0 = l15 * 64 + ((lg ^ q) << 3);         // chunks 0-3 (K 0..31)
    const int roff1 = l15 * 64 + (((4 + lg) ^ q) << 3);   // chunks 4-7 (K 32..63)
    int woff[4];
#pragma unroll
    for (int r = 0; r < 4; ++r) {
        const int wrow = lg * 4 + r;
        woff[r] = wrow * 64 + ((((col >> 3) ^ (wrow & 7))) << 3) + (col & 7);
    }

    // ---------------- B-fragments in registers ----------------
    // L0 packed: B[k][n] = W0{hi,lo}[n][(k&15)] so one MFMA does (xhi+xlo)*W0hi, next (xhi+xlo)*W0lo
    half8 bd0h, bd0l, bf0h, bf0l;
#pragma unroll
    for (int i = 0; i < 8; ++i) {
        const int idx = (lg & 1) * 8 + i;
        float vd = (idx < 15) ? dW0[col * 15 + idx] : 0.f;
        float vf = (idx < 15) ? fW0[col * 15 + idx] : 0.f;
        _Float16 h, l;
        wsplit(vd, h, l); bd0h[i] = h; bd0l[i] = l;
        wsplit(vf, h, l); bf0h[i] = h; bf0l[i] = l;
    }
    half8 bd1h0, bd1l0, bd1h1, bd1l1, bd2h0, bd2l0, bd2h1, bd2l1;
    half8 bf1h0, bf1l0, bf1h1, bf1l1, bf2h0, bf2l0, bf2h1, bf2l1;
#pragma unroll
    for (int i = 0; i < 8; ++i) {
        const int ka = lg * 8 + i, kb = 32 + lg * 8 + i;
        _Float16 h, l;
        wsplit(dW1[col * 64 + ka], h, l); bd1h0[i] = h; bd1l0[i] = l;
        wsplit(dW1[col * 64 + kb], h, l); bd1h1[i] = h; bd1l1[i] = l;
        wsplit(dW2[col * 64 + ka], h, l); bd2h0[i] = h; bd2l0[i] = l;
        wsplit(dW2[col * 64 + kb], h, l); bd2h1[i] = h; bd2l1[i] = l;
        wsplit(fW1[col * 64 + ka], h, l); bf1h0[i] = h; bf1l0[i] = l;
        wsplit(fW1[col * 64 + kb], h, l); bf1h1[i] = h; bf1l1[i] = l;
        wsplit(fW2[col * 64 + ka], h, l); bf2h0[i] = h; bf2l0[i] = l;
        wsplit(fW2[col * 64 + kb], h, l); bf2h1[i] = h; bf2l1[i] = l;
    }
    // L3: B column 0 = w3, other cols zero
    half8 w3d0, w3d1, w3f0, w3f1;
#pragma unroll
    for (int i = 0; i < 8; ++i) {
        const int ka = lg * 8 + i, kb = 32 + lg * 8 + i;
        w3d0[i] = (l15 == 0) ? (_Float16)dW3[ka] : (_Float16)0.f;
        w3d1[i] = (l15 == 0) ? (_Float16)dW3[kb] : (_Float16)0.f;
        w3f0[i] = (l15 == 0) ? (_Float16)fW3[ka] : (_Float16)0.f;
        w3f1[i] = (l15 == 0) ? (_Float16)fW3[kb] : (_Float16)0.f;
    }
    const float biasd0 = dB0[col], biasd1 = dB1[col], biasd2 = dB2[col];
    const float biasf0 = fB0[col], biasf1 = fB1[col], biasf2 = fB2[col];
    const float b3d = dB3[0], b3f = fB3[0];
    const float dt  = dtp[0];

    // ---------------- replicated per-lane state (p = lane&15) ----------------
    const int p = lane & 15;
    const int path = blockIdx.x * PPB + p;
    const size_t pathT = (size_t)path * TSTEPS;
    float iv = fminf(fmaxf(init_var[path], 0.01f), 1.5f);
    float lv = __logf(iv);
    float s1a0 = 0.f, s1a1 = 0.f;
    float s2a0 = 0.f, s2a1 = 0.f, s2a2 = 0.f, s2a3 = 0.f;
    float s3a0 = 0.f, s3a1 = 0.f, s3a2 = 0.f, s3a3 = 0.f;
    float s3a4 = 0.f, s3a5 = 0.f, s3a6 = 0.f, s3a7 = 0.f;

    for (int i = tid; i < 4 * 1024; i += NT) ((_Float16*)xpk)[i] = (_Float16)0.f;
    __syncthreads();
    _Float16* xw = xpk[wv];
    const int xwo0 = p * 64 + ((0 ^ (p & 7)) << 3);
    const int xwo1 = p * 64 + ((1 ^ (p & 7)) << 3);
    const int xwo2 = p * 64 + ((2 ^ (p & 7)) << 3);
    const int xwo3 = p * 64 + ((3 ^ (p & 7)) << 3);
    if (lane < 16) {
        _Float16 h, l; wsplit(lv + 4.0f, h, l);
        xw[xwo1 + 6] = h;   // val14 hi (chunk1 elem6)
        xw[xwo3 + 6] = l;   // val14 lo (chunk3 elem6)
    }

    for (int t = 0; t < TSTEPS; ++t) {
        const float dwv = dwg[pathT + t];   // all lanes (replicated broadcast)

        // ---- L0: packed x -> h0 (2 MFMA per MLP, full hi/lo precision) ----
        {
            const half8 a0 = *(const half8*)(xw + roff0);
            f32x4 cd = {biasd0, biasd0, biasd0, biasd0};
            f32x4 cf = {biasf0, biasf0, biasf0, biasf0};
            cd = mm(a0, bd0h, cd);  cf = mm(a0, bf0h, cf);
            cd = mm(a0, bd0l, cd);  cf = mm(a0, bf0l, cf);
#pragma unroll
            for (int r = 0; r < 4; ++r) {
                hAd[woff[r]] = (_Float16)ftanh(cd[r]);
                hAf[woff[r]] = (_Float16)ftanh(cf[r]);
            }
        }
        __syncthreads();

        // ---- L1: h0 -> h1 (2 parallel MFMA chains per MLP) ----
        {
            const half8 ad0 = *(const half8*)(hAd + roff0);
            const half8 ad1 = *(const half8*)(hAd + roff1);
            const half8 af0 = *(const half8*)(hAf + roff0);
            const half8 af1 = *(const half8*)(hAf + roff1);
            f32x4 cda = {biasd1, biasd1, biasd1, biasd1};
            f32x4 cfa = {biasf1, biasf1, biasf1, biasf1};
            f32x4 cdb = {0.f, 0.f, 0.f, 0.f}, cfb = {0.f, 0.f, 0.f, 0.f};
            cda = mm(ad0, bd1h0, cda);  cfa = mm(af0, bf1h0, cfa);
            cdb = mm(ad0, bd1l0, cdb);  cfb = mm(af0, bf1l0, cfb);
            cda = mm(ad1, bd1h1, cda);  cfa = mm(af1, bf1h1, cfa);
            cdb = mm(ad1, bd1l1, cdb);  cfb = mm(af1, bf1l1, cfb);
            const f32x4 cd = cda + cdb, cf = cfa + cfb;
#pragma unroll
            for (int r = 0; r < 4; ++r) {
                hBd[woff[r]] = (_Float16)ftanh(cd[r]);
                hBf[woff[r]] = (_Float16)ftanh(cf[r]);
            }
        }
        __syncthreads();

        // ---- L2: h1 -> h2 (tanh'd, f16, into hC) ----
        {
            const half8 ad0 = *(const half8*)(hBd + roff0);
            const half8 ad1 = *(const half8*)(hBd + roff1);
            const half8 af0 = *(const half8*)(hBf + roff0);
            const half8 af1 = *(const half8*)(hBf + roff1);
            f32x4 cda = {biasd2, biasd2, biasd2, biasd2};
            f32x4 cfa = {biasf2, biasf2, biasf2, biasf2};
            f32x4 cdb = {0.f, 0.f, 0.f, 0.f}, cfb = {0.f, 0.f, 0.f, 0.f};
            cda = mm(ad0, bd2h0, cda);  cfa = mm(af0, bf2h0, cfa);
            cdb = mm(ad0, bd2l0, cdb);  cfb = mm(af0, bf2l0, cfb);
            cda = mm(ad1, bd2h1, cda);  cfa = mm(af1, bf2h1, cfa);
            cdb = mm(ad1, bd2l1, cdb);  cfb = mm(af1, bf2l1, cfb);
            const f32x4 cd = cda + cdb, cf = cfa + cfb;
#pragma unroll
            for (int r = 0; r < 4; ++r) {
                hCd[woff[r]] = (_Float16)ftanh(cd[r]);
                hCf[woff[r]] = (_Float16)ftanh(cf[r]);
            }
        }
        __syncthreads();

        // ---- L3 (redundant in every wave): h2 . w3 via MFMA, col 0 ----
        float od, of;
        {
            const half8 ad0 = *(const half8*)(hCd + roff0);
            const half8 ad1 = *(const half8*)(hCd + roff1);
            const half8 af0 = *(const half8*)(hCf + roff0);
            const half8 af1 = *(const half8*)(hCf + roff1);
            f32x4 c3d = {0.f, 0.f, 0.f, 0.f}, c3f = {0.f, 0.f, 0.f, 0.f};
            c3d = mm(ad0, w3d0, c3d);  c3f = mm(af0, w3f0, c3f);
            c3d = mm(ad1, w3d1, c3d);  c3f = mm(af1, w3f1, c3f);
            // C[p][0] lives in lane (p>>2)*16, reg p&3
            const int src = (p >> 2) << 4;
            const float gd0 = __shfl(c3d[0], src), gd1 = __shfl(c3d[1], src);
            const float gd2 = __shfl(c3d[2], src), gd3 = __shfl(c3d[3], src);
            const float gf0 = __shfl(c3f[0], src), gf1 = __shfl(c3f[1], src);
            const float gf2 = __shfl(c3f[2], src), gf3 = __shfl(c3f[3], src);
            od = ((p & 2) ? ((p & 1) ? gd3 : gd2) : ((p & 1) ? gd1 : gd0)) + b3d;
            of = ((p & 2) ? ((p & 1) ? gf3 : gf2) : ((p & 1) ? gf1 : gf0)) + b3f;
        }

        // ---- replicated state update (all lanes, p = lane&15) ----
        {
            const float drift_nn = 0.5f * ftanh(od);
            const float diffu = 1.5f * fsigm(of) + 0.1f;
            float lvn = lv + KAPPA * (THETA - lv) * dt + drift_nn * dt + diffu * dwv;
            lvn = fminf(fmaxf(lvn, -5.0f), 1.0f);
            const float d = lvn - lv;
            const float o0 = dt * dt, o1 = dt * d, o2 = d * dt, o3 = d * d;
            const float c6 = 1.0f / 6.0f;
            s3a0 += s2a0 * dt + s1a0 * 0.5f * o0 + dt * o0 * c6;
            s3a1 += s2a0 * d  + s1a0 * 0.5f * o1 + dt * o1 * c6;
            s3a2 += s2a1 * dt + s1a0 * 0.5f * o2 + dt * o2 * c6;
            s3a3 += s2a1 * d  + s1a0 * 0.5f * o3 + dt * o3 * c6;
            s3a4 += s2a2 * dt + s1a1 * 0.5f * o0 + d * o0 * c6;
            s3a5 += s2a2 * d  + s1a1 * 0.5f * o1 + d * o1 * c6;
            s3a6 += s2a3 * dt + s1a1 * 0.5f * o2 + d * o2 * c6;
            s3a7 += s2a3 * d  + s1a1 * 0.5f * o3 + d * o3 * c6;
            s2a0 += s1a0 * dt + 0.5f * o0;  s2a1 += s1a0 * d + 0.5f * o1;
            s2a2 += s1a1 * dt + 0.5f * o2;  s2a3 += s1a1 * d + 0.5f * o3;
            s1a0 += dt;  s1a1 += d;
            if (tid < 16) out[pathT + t] = __expf(lvn);   // wave 0 only stores
            lv = lvn;
        }

        // ---- wave-private x rebuild (lanes 0-15), no barrier needed ----
        if (lane < 16) {
            const float v[16] = {s1a0, s1a1, s2a0, s2a1, s2a2, s2a3, s3a0, s3a1,
                                 s3a2, s3a3, s3a4, s3a5, s3a6, s3a7, lv + 4.0f, 0.f};
            half8 h0v, h1v, l0v, l1v;
#pragma unroll
            for (int i = 0; i < 8; ++i) {
                _Float16 h, l;
                wsplit(v[i], h, l);     h0v[i] = h; l0v[i] = l;
                wsplit(v[8 + i], h, l); h1v[i] = h; l1v[i] = l;
            }
            *(half8*)(xw + xwo0) = h0v;
            *(half8*)(xw + xwo1) = h1v;
            *(half8*)(xw + xwo2) = l0v;
            *(half8*)(xw + xwo3) = l1v;
        }
        // next L0 reads xw (same wave; ordered by lgkmcnt). hA rewrite is safe:
        // all waves passed B3, so every wave finished its L1 reads of hA.
    }
}

extern "C" void kernel_launch(void* const* d_in, const int* in_sizes, int n_in,
                              void* d_out, int out_size, void* d_ws, size_t ws_size,
                              hipStream_t stream) {
    const float* init_var = (const float*)d_in[0];
    const float* dtp      = (const float*)d_in[1];
    const float* dwg      = (const float*)d_in[2];
    const float* dW0 = (const float*)d_in[3];
    const float* dB0 = (const float*)d_in[4];
    const float* dW1 = (const float*)d_in[5];
    const float* dB1 = (const float*)d_in[6];
    const float* dW2 = (const float*)d_in[7];
    const float* dB2 = (const float*)d_in[8];
    const float* dW3 = (const float*)d_in[9];
    const float* dB3 = (const float*)d_in[10];
    const float* fW0 = (const float*)d_in[11];
    const float* fB0 = (const float*)d_in[12];
    const float* fW1 = (const float*)d_in[13];
    const float* fB1 = (const float*)d_in[14];
    const float* fW2 = (const float*)d_in[15];
    const float* fB2 = (const float*)d_in[16];
    const float* fW3 = (const float*)d_in[17];
    const float* fB3 = (const float*)d_in[18];
    float* out = (float*)d_out;

    sim_kernel<<<dim3(8192 / PPB), dim3(NT), 0, stream>>>(
        init_var, dtp, dwg,
        dW0, dB0, dW1, dB1, dW2, dB2, dW3, dB3,
        fW0, fB0, fW1, fB1, fW2, fB2, fW3, fB3,
        out);
}